// Round 16
// baseline (1165.365 us; speedup 1.0000x reference)
//
#include <hip/hip_runtime.h>
#include <hip/hip_bf16.h>

#define VOCAB 32000
#define EMBED 256
#define HIDDEN 512
#define BB 64
#define SS 64
#define M_ROWS (BB * SS)       /* 4096 */
#define G4 (4 * HIDDEN)        /* 2048 */
#define NBLK 16                /* LSTM blocks */
#define NTOT 256               /* mega-kernel blocks (all CUs) */
#define NTILE_N (VOCAB / 256)  /* 125 */
#define NITEM 1000             /* 750 chunked (hm<30) + 250 fine (hm>=30) */

typedef __attribute__((ext_vector_type(8))) short short8v;
typedef __attribute__((ext_vector_type(4))) float float4v;
typedef __attribute__((ext_vector_type(4))) unsigned int uint4v;

__device__ __forceinline__ ushort f2bf(float f) {
    union { float f; unsigned u; } v; v.f = f;
    unsigned r = (v.u + 0x7FFFu + ((v.u >> 16) & 1u)) >> 16;
    return (ushort)r;
}

__device__ __forceinline__ float fast_tanh(float x) {
    float xc = fminf(fmaxf(x, -15.f), 15.f);
    float e = __expf(2.f * xc);
    return (e - 1.f) / (e + 1.f);
}

__device__ __forceinline__ void glds16(const ushort* g, ushort* l) {
    __builtin_amdgcn_global_load_lds(
        (const __attribute__((address_space(1))) unsigned int*)(const void*)g,
        (__attribute__((address_space(3))) unsigned int*)(void*)l, 16, 0, 0);
}

// strided f32 -> bf16 row-block convert
__global__ void k_conv_strided(const float* __restrict__ in, ushort* __restrict__ out,
                               int lg2cols, int instride, int n8) {
    int i = blockIdx.x * blockDim.x + threadIdx.x;
    int stride = gridDim.x * blockDim.x;
    int colmask = (1 << lg2cols) - 1;
    for (; i < n8; i += stride) {
        int i8 = i << 3;
        int row = i8 >> lg2cols, col = i8 & colmask;
        const float* src = in + (size_t)row * instride + col;
        float4 v0 = *(const float4*)src;
        float4 v1 = *(const float4*)(src + 4);
        short8v o;
        o[0] = (short)f2bf(v0.x); o[1] = (short)f2bf(v0.y);
        o[2] = (short)f2bf(v0.z); o[3] = (short)f2bf(v0.w);
        o[4] = (short)f2bf(v1.x); o[5] = (short)f2bf(v1.y);
        o[6] = (short)f2bf(v1.z); o[7] = (short)f2bf(v1.w);
        *(short8v*)(out + i8) = o;
    }
}

// embedding gather -> bf16 [4096][256]
__global__ void k_build_emb(const int* __restrict__ tseq, const float* __restrict__ emb,
                            ushort* __restrict__ embbf) {
    int rid = blockIdx.x * 8 + (threadIdx.x >> 5);
    int c0 = (threadIdx.x & 31) * 8;
    int tok = tseq[rid];
    const float* src = emb + (size_t)tok * EMBED + c0;
    float4 v0 = *(const float4*)src;
    float4 v1 = *(const float4*)(src + 4);
    short8v o;
    o[0] = (short)f2bf(v0.x); o[1] = (short)f2bf(v0.y);
    o[2] = (short)f2bf(v0.z); o[3] = (short)f2bf(v0.w);
    o[4] = (short)f2bf(v1.x); o[5] = (short)f2bf(v1.y);
    o[6] = (short)f2bf(v1.z); o[7] = (short)f2bf(v1.w);
    *(short8v*)(embbf + (size_t)rid * EMBED + c0) = o;
}

// prep: biases, ctx bf16, ctrl zero, h0 -> stamped mailbox A (stamp=1), B stamps=0
__global__ void k_prep_small(const float* __restrict__ b_ih, const float* __restrict__ b_hh,
                             float* __restrict__ bias_pre,
                             const float* __restrict__ h0,
                             uint4* __restrict__ mboxA, uint4* __restrict__ mboxB,
                             const float* __restrict__ ctx, ushort* __restrict__ ctx_bf,
                             unsigned* __restrict__ ctrl) {
    int i = blockIdx.x * blockDim.x + threadIdx.x;
    if (i < 1024) ctrl[i] = 0;   // flags + queue zeroed every launch (replay-safe)
    if (i < G4) bias_pre[i] = b_ih[i] + b_hh[i];
    if (i < BB * HIDDEN) ctx_bf[i] = f2bf(ctx[i]);
    if (i < BB * 128) {          // 8192 mailbox units
        int b = i >> 7, u = i & 127;
        const float* src = h0 + (size_t)b * HIDDEN + u * 4;
        unsigned lo = (unsigned)f2bf(src[0]) | ((unsigned)f2bf(src[1]) << 16);
        unsigned hi = (unsigned)f2bf(src[2]) | ((unsigned)f2bf(src[3]) << 16);
        uint4 va; va.x = lo; va.y = hi; va.z = 1u; va.w = 0u;
        mboxA[i] = va;
        uint4 vz; vz.x = 0u; vz.y = 0u; vz.z = 0u; vz.w = 0u;
        mboxB[i] = vz;
    }
}

// Small-M GEMM: Cout[64][N] = Abf[64][512](bf16) @ Wf[N][.]^T(f32 strided) + bias[N].
__global__ __launch_bounds__(256) void k_gemm_smallM(
    const ushort* __restrict__ Abf, const float* __restrict__ Wf, int wstride,
    const float* __restrict__ bias, float* __restrict__ Cout, int N) {
    int t = threadIdx.x;
    int wv = t >> 6, lane = t & 63, lr = lane & 15, kg = lane >> 4;
    int bcol = blockIdx.x * 128;

    float4v acc[4][2];
#pragma unroll
    for (int m = 0; m < 4; m++)
#pragma unroll
        for (int n = 0; n < 2; n++) acc[m][n] = (float4v){0.f, 0.f, 0.f, 0.f};

#pragma unroll 4
    for (int ks = 0; ks < 16; ks++) {
        short8v a[4];
#pragma unroll
        for (int m = 0; m < 4; m++)
            a[m] = *(const short8v*)(Abf + (size_t)(m * 16 + lr) * 512 + ks * 32 + kg * 8);
        short8v w[2];
#pragma unroll
        for (int n = 0; n < 2; n++) {
            const float* src = Wf + (size_t)(bcol + wv * 32 + n * 16 + lr) * wstride + ks * 32 + kg * 8;
            float4 v0 = *(const float4*)src;
            float4 v1 = *(const float4*)(src + 4);
            short8v w8;
            w8[0] = (short)f2bf(v0.x); w8[1] = (short)f2bf(v0.y);
            w8[2] = (short)f2bf(v0.z); w8[3] = (short)f2bf(v0.w);
            w8[4] = (short)f2bf(v1.x); w8[5] = (short)f2bf(v1.y);
            w8[6] = (short)f2bf(v1.z); w8[7] = (short)f2bf(v1.w);
            w[n] = w8;
        }
#pragma unroll
        for (int m = 0; m < 4; m++)
#pragma unroll
            for (int n = 0; n < 2; n++)
                acc[m][n] = __builtin_amdgcn_mfma_f32_16x16x32_bf16(a[m], w[n], acc[m][n], 0, 0, 0);
    }

#pragma unroll
    for (int n = 0; n < 2; n++) {
        int col = bcol + wv * 32 + n * 16 + lr;
        float bv = bias[col];
#pragma unroll
        for (int m = 0; m < 4; m++) {
            int row = m * 16 + kg * 4;
#pragma unroll
            for (int j = 0; j < 4; j++)
                Cout[(size_t)(row + j) * N + col] = acc[m][n][j] + bv;
        }
    }
}

// Standalone 256x256 GEMM (pre only): C = A@W^T + rowbias[row>>6], b-major rows.
__global__ __launch_bounds__(512) void k_gemm_bf16(
    const ushort* __restrict__ A, const ushort* __restrict__ W,
    const float* __restrict__ rowbias, float* __restrict__ C,
    int M, int N, int K) {
    __shared__ ushort As[256 * 32];
    __shared__ ushort Ws[256 * 32];
    int t = threadIdx.x;

    int gx = N >> 8, gy = M >> 8;
    int nwg = gx * gy;
    int q = nwg >> 3, r = nwg & 7;
    int xcd = blockIdx.x & 7, idx = blockIdx.x >> 3;
    int wg = (xcd < r) ? xcd * (q + 1) + idx : r * (q + 1) + (xcd - r) * q + idx;
    const int SG = 4;
    int grp = wg / (gx * SG);
    int rem = wg % (gx * SG);
    int bx = rem / SG;
    int by = grp * SG + rem % SG;
    int brow = by * 256, bcol = bx * 256;

    int wave = t >> 6, lane = t & 63;
    int wr = wave >> 2, wc = wave & 3;
    int lr = lane & 15, kg = lane >> 4;

    float4v acc[8][4];
#pragma unroll
    for (int m = 0; m < 8; m++)
#pragma unroll
        for (int n = 0; n < 4; n++) acc[m][n] = (float4v){0.f, 0.f, 0.f, 0.f};

    int srow = t >> 2;
    int scol = (((t & 3) ^ (srow & 3))) * 8;
    const ushort* AgA = A + (size_t)(brow + srow) * K + scol;
    const ushort* AgB = A + (size_t)(brow + 128 + srow) * K + scol;
    const ushort* WgA = W + (size_t)(bcol + srow) * K + scol;
    const ushort* WgB = W + (size_t)(bcol + 128 + srow) * K + scol;
    ushort* ldsA0 = &As[(wave * 16) * 32];
    ushort* ldsA1 = &As[(128 + wave * 16) * 32];
    ushort* ldsW0 = &Ws[(wave * 16) * 32];
    ushort* ldsW1 = &Ws[(128 + wave * 16) * 32];

    for (int bk = 0; bk < K; bk += 32) {
        glds16(AgA + bk, ldsA0);
        glds16(AgB + bk, ldsA1);
        glds16(WgA + bk, ldsW0);
        glds16(WgB + bk, ldsW1);
        __syncthreads();
        short8v a[8], w[4];
#pragma unroll
        for (int m = 0; m < 8; m++) {
            int row = wr * 128 + m * 16 + lr;
            a[m] = *(const short8v*)&As[row * 32 + (kg ^ (row & 3)) * 8];
        }
#pragma unroll
        for (int n = 0; n < 4; n++) {
            int row = wc * 64 + n * 16 + lr;
            w[n] = *(const short8v*)&Ws[row * 32 + (kg ^ (row & 3)) * 8];
        }
#pragma unroll
        for (int m = 0; m < 8; m++)
#pragma unroll
            for (int n = 0; n < 4; n++)
                acc[m][n] = __builtin_amdgcn_mfma_f32_16x16x32_bf16(a[m], w[n], acc[m][n], 0, 0, 0);
        __syncthreads();
    }

#pragma unroll
    for (int n = 0; n < 4; n++) {
        int col = bcol + wc * 64 + n * 16 + lr;
#pragma unroll
        for (int m = 0; m < 8; m++) {
            int row = brow + wr * 128 + m * 16 + kg * 4;
            float bv = rowbias[(size_t)(row >> 6) * N + col];
            float4v v = acc[m][n];
#pragma unroll
            for (int j = 0; j < 4; j++)
                C[(size_t)(row + j) * N + col] = v[j] + bv;
        }
    }
}

// MEGA kernel: blocks 0..15 = persistent LSTM with STAMP-VALIDATED MAILBOX
// h-exchange (16B units [8B data|4B stamp|4B pad], single dwordx4 sc0sc1
// stores/loads = atomic snapshots; reader retries stale units — no flag RT,
// no poll RT on the recurrence critical path). Workers (16..255) = r15
// structure: (hm 128-row group, chunk) items, LDS-resident A, cached-W
// glds16 K-loop, nontemporal C. flags only gate workers now.
__global__ __launch_bounds__(512) void k_mega(
    const float* __restrict__ pre, const float* __restrict__ w_hh,
    const float* __restrict__ c0,
    uint4* __restrict__ mboxA, uint4* __restrict__ mboxB,
    ushort* __restrict__ out_in, unsigned* __restrict__ ctrl,
    const ushort* __restrict__ Wfc, const float* __restrict__ ctxdot,
    float* __restrict__ Cout) {
    __shared__ __align__(16) char smem[147456];
    __shared__ int s_tile;
    unsigned* flags = ctrl;
    unsigned* queue = ctrl + 512;
    int t = threadIdx.x;
    int bid = blockIdx.x;
    int wave = t >> 6, lane = t & 63, lr = lane & 15, kg = lane >> 4;

    if (bid < NBLK) {
        // ================= LSTM path =================
        ushort* h_lds = (ushort*)smem;
        float* G2 = (float*)(smem + 65536);
        char* hl = (char*)h_lds;
        int p = bid;
        int w = wave;
        int mh = w >> 2, cw2 = w & 3;

        short8v wfrag[2][16];
#pragma unroll
        for (int ci = 0; ci < 2; ci++) {
            const float* wrow = w_hh + (size_t)(cw2 * HIDDEN + p * 32 + ci * 16 + lr) * HIDDEN;
#pragma unroll
            for (int ks = 0; ks < 16; ks++) {
                const float* src = wrow + ks * 32 + kg * 8;
                short8v w8;
#pragma unroll
                for (int e = 0; e < 8; e++) w8[e] = (short)f2bf(src[e]);
                wfrag[ci][ks] = w8;
            }
        }

        int b = t >> 3, jj0 = (t & 7) * 4, jg0 = p * 32 + jj0;
        float4v c_reg = *(const float4v*)(c0 + (size_t)b * HIDDEN + jg0);
        float4v pv[4];
#pragma unroll
        for (int qg = 0; qg < 4; qg++)
            pv[qg] = *(const float4v*)(pre + (size_t)(b * SS) * G4 + qg * HIDDEN + jg0);

        for (int s = 0; s < SS; s++) {
            // ---- stage h from stamped mailbox (retry stale units) ----
            {
                const char* mb = (const char*)((s & 1) ? mboxB : mboxA);
                unsigned expect = (unsigned)(s + 1);
                uint4v vb[16];
                unsigned stale = 0xFFFFu;
                while (stale) {
#pragma unroll
                    for (int i = 0; i < 8; i++)
#pragma unroll
                        for (int h2 = 0; h2 < 2; h2++) {
                            int k = i * 2 + h2;
                            if (stale & (1u << k)) {
                                const void* src = mb + ((size_t)(w * 8 + i) * 128 + lane * 2 + h2) * 16;
                                asm volatile("global_load_dwordx4 %0, %1, off sc0 sc1"
                                             : "=&v"(vb[k]) : "v"(src));
                            }
                        }
                    asm volatile("s_waitcnt vmcnt(0)" ::: "memory");
#pragma unroll
                    for (int k = 0; k < 16; k++)
                        if ((stale & (1u << k)) && vb[k][2] == expect) stale &= ~(1u << k);
                }
#pragma unroll
                for (int i = 0; i < 8; i++) {
                    int rr = w * 8 + i;
                    uint4v v;
                    v[0] = vb[i * 2][0]; v[1] = vb[i * 2][1];
                    v[2] = vb[i * 2 + 1][0]; v[3] = vb[i * 2 + 1][1];
                    int off = (rr * 1024 + lane * 16) ^ ((rr & 7) << 4);
                    *(uint4v*)(hl + off) = v;
                }
            }
            __syncthreads();

            float4v acc[2][2];
#pragma unroll
            for (int mi = 0; mi < 2; mi++)
#pragma unroll
                for (int ci = 0; ci < 2; ci++) acc[mi][ci] = (float4v){0.f, 0.f, 0.f, 0.f};
#pragma unroll
            for (int ks = 0; ks < 16; ks++) {
                short8v a[2];
#pragma unroll
                for (int mi = 0; mi < 2; mi++) {
                    int row = mh * 32 + mi * 16 + lr;
                    int off = (row * 1024 + ks * 64 + kg * 16) ^ ((row & 7) << 4);
                    a[mi] = *(const short8v*)(hl + off);
                }
#pragma unroll
                for (int mi = 0; mi < 2; mi++)
#pragma unroll
                    for (int ci = 0; ci < 2; ci++)
                        acc[mi][ci] = __builtin_amdgcn_mfma_f32_16x16x32_bf16(a[mi], wfrag[ci][ks], acc[mi][ci], 0, 0, 0);
            }
#pragma unroll
            for (int mi = 0; mi < 2; mi++)
#pragma unroll
                for (int ci = 0; ci < 2; ci++)
#pragma unroll
                    for (int rr = 0; rr < 4; rr++)
                        G2[(mh * 32 + mi * 16 + kg * 4 + rr) * 132 + cw2 * 32 + ci * 16 + lr] = acc[mi][ci][rr];
            __syncthreads();

            {
                float4v gq[4];
#pragma unroll
                for (int qg = 0; qg < 4; qg++) gq[qg] = *(const float4v*)&G2[b * 132 + qg * 32 + jj0];
                unsigned long long hv8 = 0;
#pragma unroll
                for (int e = 0; e < 4; e++) {
                    float xi = gq[0][e] + pv[0][e];
                    float xf = gq[1][e] + pv[1][e];
                    float xg = gq[2][e] + pv[2][e];
                    float xo = gq[3][e] + pv[3][e];
                    float ig = 1.f / (1.f + __expf(-xi));
                    float fg = 1.f / (1.f + __expf(-xf));
                    float gg = fast_tanh(xg);
                    float og = 1.f / (1.f + __expf(-xo));
                    float cn = fg * c_reg[e] + ig * gg;
                    float hv = og * fast_tanh(cn);
                    c_reg[e] = cn;
                    hv8 |= (unsigned long long)f2bf(hv) << (16 * e);
                }
                if (s + 1 < SS) {
                    // mailbox publish: 16B atomic unit [data|stamp s+2|0]
                    uint4v pub;
                    pub[0] = (unsigned)(hv8 & 0xFFFFFFFFull);
                    pub[1] = (unsigned)(hv8 >> 32);
                    pub[2] = (unsigned)(s + 2);
                    pub[3] = 0u;
                    char* mbn = (char*)((s & 1) ? (void*)mboxA : (void*)mboxB);
                    const void* dst = mbn + ((size_t)(b * 128 + p * 8 + (t & 7)) * 16);
                    asm volatile("global_store_dwordx4 %0, %1, off sc0 sc1"
                                 :: "v"(dst), "v"(pub) : "memory");
                }
                // s-major publish for the GEMM workers (agent scope)
                __hip_atomic_store((unsigned long long*)(out_in + (size_t)(s * BB + b) * HIDDEN + jg0), hv8,
                                   __ATOMIC_RELAXED, __HIP_MEMORY_SCOPE_AGENT);
                if (s + 1 < SS) {
#pragma unroll
                    for (int qg = 0; qg < 4; qg++)
                        pv[qg] = *(const float4v*)(pre + (size_t)(b * SS + s + 1) * G4 + qg * HIDDEN + jg0);
                }
            }

            __syncthreads();   // drains all sc0sc1 stores (vmcnt) block-wide
            if (t == 0)
                __hip_atomic_store(flags + p * 16, (unsigned)(s + 1),
                                   __ATOMIC_RELEASE, __HIP_MEMORY_SCOPE_AGENT);
        }
    } else {
        // ================= GEMM worker path (r15) =================
        ushort* As = (ushort*)smem;               // 128KB resident A (swizzled)
        ushort* Ws = (ushort*)(smem + 131072);    // 16KB W staging
        char* al = (char*)As;
        int srow = t >> 2;                        // 0..127 (W staging row)
        int scolW = ((t & 3) ^ (srow & 3)) * 8;
        ushort* ldsW0 = Ws + (wave * 16) * 32;
        ushort* ldsW1 = Ws + (128 + wave * 16) * 32;
        int wr = wave >> 2, wc = wave & 3;
        int last_hm = -1, last_gated = -1;

        for (;;) {
            __syncthreads();
            if (t == 0)
                s_tile = (int)__hip_atomic_fetch_add(queue, 1u, __ATOMIC_RELAXED, __HIP_MEMORY_SCOPE_AGENT);
            __syncthreads();
            int item = s_tile;
            if (item >= NITEM) break;
            int hm, nt0, cnt;
            if (item < 750) { hm = item / 25; nt0 = (item % 25) * 5; cnt = 5; }
            else { int j = item - 750; hm = 30 + j / 125; nt0 = j % 125; cnt = 1; }

            int need = 2 * hm + 2;
            if (need > last_gated) {
                if (wave == 0) {
                    const unsigned* fp = flags + (lane & 15) * 16;
                    for (;;) {
                        unsigned fv = __hip_atomic_load(fp, __ATOMIC_RELAXED, __HIP_MEMORY_SCOPE_AGENT);
                        if (__all((int)(fv >= (unsigned)need))) break;
                        asm volatile("s_sleep 32");
                    }
                }
                __syncthreads();
                last_gated = need;
            }

            if (hm != last_hm) {
                // load A rows [hm*128, +128) into resident LDS (sc0sc1, swizzled)
                const ushort* Ab = out_in + (size_t)hm * 128 * HIDDEN;
#pragma unroll
                for (int half = 0; half < 2; half++) {
                    uint4v vb[8];
#pragma unroll
                    for (int i = 0; i < 8; i++) {
                        int rr = wave * 16 + half * 8 + i;
                        const void* src = Ab + (size_t)rr * HIDDEN + lane * 8;
                        asm volatile("global_load_dwordx4 %0, %1, off sc0 sc1"
                                     : "=&v"(vb[i]) : "v"(src));
                    }
                    asm volatile("s_waitcnt vmcnt(0)" ::: "memory");
#pragma unroll
                    for (int i = 0; i < 8; i++) {
                        int rr = wave * 16 + half * 8 + i;
                        int off = (rr * 1024 + lane * 16) ^ ((rr & 7) << 4);
                        *(uint4v*)(al + off) = vb[i];
                    }
                }
                __syncthreads();
                last_hm = hm;
            }

            for (int q5 = 0; q5 < cnt; q5++) {
                int nt = nt0 + q5;
                int bcol = nt * 256;

                float4v acc[4][4];
#pragma unroll
                for (int m = 0; m < 4; m++)
#pragma unroll
                    for (int n = 0; n < 4; n++) acc[m][n] = (float4v){0.f, 0.f, 0.f, 0.f};

                const ushort* WgA = Wfc + (size_t)(bcol + srow) * HIDDEN + scolW;
                const ushort* WgB = WgA + (size_t)128 * HIDDEN;

                for (int ks = 0; ks < 16; ks++) {
                    glds16(WgA + ks * 32, ldsW0);
                    glds16(WgB + ks * 32, ldsW1);
                    __syncthreads();
                    short8v a[4], w[4];
#pragma unroll
                    for (int m = 0; m < 4; m++) {
                        int row = wr * 64 + m * 16 + lr;
                        int off = (row * 1024 + ks * 64 + kg * 16) ^ ((row & 7) << 4);
                        a[m] = *(const short8v*)(al + off);
                    }
#pragma unroll
                    for (int n = 0; n < 4; n++) {
                        int wrow = wc * 64 + n * 16 + lr;
                        w[n] = *(const short8v*)&Ws[wrow * 32 + (kg ^ (wrow & 3)) * 8];
                    }
#pragma unroll
                    for (int m = 0; m < 4; m++)
#pragma unroll
                        for (int n = 0; n < 4; n++)
                            acc[m][n] = __builtin_amdgcn_mfma_f32_16x16x32_bf16(a[m], w[n], acc[m][n], 0, 0, 0);
                    __syncthreads();
                }

                // epilogue: local row rl -> (s = hm*2 + rl>>6, b = rl&63)
#pragma unroll
                for (int n = 0; n < 4; n++) {
                    int col = bcol + wc * 64 + n * 16 + lr;
#pragma unroll
                    for (int m = 0; m < 4; m++) {
                        int rbase = wr * 64 + m * 16 + kg * 4;
#pragma unroll
                        for (int j = 0; j < 4; j++) {
                            int rl = rbase + j;
                            int bb = rl & 63;
                            int ss = hm * 2 + (rl >> 6);
                            float val = acc[m][n][j] + ctxdot[(size_t)bb * VOCAB + col];
                            __builtin_nontemporal_store(val, &Cout[(size_t)(bb * 64 + ss) * VOCAB + col]);
                        }
                    }
                }
            }
        }
    }
}

extern "C" void kernel_launch(void* const* d_in, const int* in_sizes, int n_in,
                              void* d_out, int out_size, void* d_ws, size_t ws_size,
                              hipStream_t stream) {
    const int*   tseq = (const int*)d_in[0];
    const float* ctx  = (const float*)d_in[1];
    const float* h0   = (const float*)d_in[2];
    const float* c0   = (const float*)d_in[3];
    const float* emb  = (const float*)d_in[4];
    const float* w_ih = (const float*)d_in[5];
    const float* w_hh = (const float*)d_in[6];
    const float* b_ih = (const float*)d_in[7];
    const float* b_hh = (const float*)d_in[8];
    const float* w_fc = (const float*)d_in[9];
    const float* b_fc = (const float*)d_in[10];
    float* out = (float*)d_out;

    char* wsb = (char*)d_ws;
    size_t off = 0;
    auto alloc = [&](size_t bytes) -> void* {
        void* ptr = wsb + off;
        off = (off + bytes + 255) & ~(size_t)255;
        return ptr;
    };
    ushort* emb_bf    = (ushort*)alloc((size_t)M_ROWS * EMBED * 2);
    ushort* w_ih_ebf  = (ushort*)alloc((size_t)G4 * EMBED * 2);
    ushort* w_fc_hbf  = (ushort*)alloc((size_t)VOCAB * HIDDEN * 2);
    ushort* out_in    = (ushort*)alloc((size_t)M_ROWS * HIDDEN * 2);
    float*  pre       = (float*)alloc((size_t)M_ROWS * G4 * 4);
    float*  prectx    = (float*)alloc((size_t)BB * G4 * 4);
    float*  ctxdot    = (float*)alloc((size_t)BB * VOCAB * 4);
    ushort* ctx_bf    = (ushort*)alloc((size_t)BB * HIDDEN * 2);
    uint4*  mboxA     = (uint4*)alloc((size_t)BB * 128 * 16);
    uint4*  mboxB     = (uint4*)alloc((size_t)BB * 128 * 16);
    float*  bias_pre  = (float*)alloc((size_t)G4 * 4);
    unsigned* ctrl    = (unsigned*)alloc(4096);

    k_conv_strided<<<256, 256, 0, stream>>>(w_ih, w_ih_ebf, 8, 768, G4 * EMBED / 8);
    k_conv_strided<<<2048, 256, 0, stream>>>(w_fc, w_fc_hbf, 9, 1024, VOCAB * HIDDEN / 8);
    k_build_emb<<<M_ROWS / 8, 256, 0, stream>>>(tseq, emb, emb_bf);
    k_prep_small<<<128, 256, 0, stream>>>(b_ih, b_hh, bias_pre, h0, mboxA, mboxB, ctx, ctx_bf, ctrl);

    // ctx row-bias GEMMs (64 unique rows)
    k_gemm_smallM<<<G4 / 128, 256, 0, stream>>>(ctx_bf, w_ih + 256, 768, bias_pre, prectx, G4);
    k_gemm_smallM<<<VOCAB / 128, 256, 0, stream>>>(ctx_bf, w_fc + 512, 1024, b_fc, ctxdot, VOCAB);

    // pre = emb_bf @ w_ih_emb^T + prectx[b]   (K=256)
    k_gemm_bf16<<<dim3((G4 / 256) * (M_ROWS / 256)), 512, 0, stream>>>(
        emb_bf, w_ih_ebf, prectx, pre, M_ROWS, G4, EMBED);

    // fused LSTM + gated logits GEMM on all 256 CUs
    void* args[] = {(void*)&pre, (void*)&w_hh, (void*)&c0,
                    (void*)&mboxA, (void*)&mboxB, (void*)&out_in, (void*)&ctrl,
                    (void*)&w_fc_hbf, (void*)&ctxdot, (void*)&out};
    hipLaunchCooperativeKernel((void*)k_mega, dim3(NTOT), dim3(512), args, 0, stream);
}

// Round 17
// 649.913 us; speedup vs baseline: 1.7931x; 1.7931x over previous
//
#include <hip/hip_runtime.h>
#include <hip/hip_bf16.h>

#define VOCAB 32000
#define EMBED 256
#define HIDDEN 512
#define BB 64
#define SS 64
#define M_ROWS (BB * SS)       /* 4096 */
#define G4 (4 * HIDDEN)        /* 2048 */
#define NBLK 16                /* LSTM blocks */
#define NTOT 256               /* mega-kernel blocks (all CUs) */
#define NTILE_N (VOCAB / 256)  /* 125 */
#define NITEM 1000             /* 750 chunked (hm<30) + 250 fine (hm>=30) */

typedef __attribute__((ext_vector_type(8))) short short8v;
typedef __attribute__((ext_vector_type(4))) float float4v;
typedef __attribute__((ext_vector_type(4))) unsigned int uint4v;

__device__ __forceinline__ ushort f2bf(float f) {
    union { float f; unsigned u; } v; v.f = f;
    unsigned r = (v.u + 0x7FFFu + ((v.u >> 16) & 1u)) >> 16;
    return (ushort)r;
}

__device__ __forceinline__ float fast_tanh(float x) {
    float xc = fminf(fmaxf(x, -15.f), 15.f);
    float e = __expf(2.f * xc);
    return (e - 1.f) / (e + 1.f);
}

__device__ __forceinline__ void glds16(const ushort* g, ushort* l) {
    __builtin_amdgcn_global_load_lds(
        (const __attribute__((address_space(1))) unsigned int*)(const void*)g,
        (__attribute__((address_space(3))) unsigned int*)(void*)l, 16, 0, 0);
}

// strided f32 -> bf16 row-block convert
__global__ void k_conv_strided(const float* __restrict__ in, ushort* __restrict__ out,
                               int lg2cols, int instride, int n8) {
    int i = blockIdx.x * blockDim.x + threadIdx.x;
    int stride = gridDim.x * blockDim.x;
    int colmask = (1 << lg2cols) - 1;
    for (; i < n8; i += stride) {
        int i8 = i << 3;
        int row = i8 >> lg2cols, col = i8 & colmask;
        const float* src = in + (size_t)row * instride + col;
        float4 v0 = *(const float4*)src;
        float4 v1 = *(const float4*)(src + 4);
        short8v o;
        o[0] = (short)f2bf(v0.x); o[1] = (short)f2bf(v0.y);
        o[2] = (short)f2bf(v0.z); o[3] = (short)f2bf(v0.w);
        o[4] = (short)f2bf(v1.x); o[5] = (short)f2bf(v1.y);
        o[6] = (short)f2bf(v1.z); o[7] = (short)f2bf(v1.w);
        *(short8v*)(out + i8) = o;
    }
}

// embedding gather -> bf16 [4096][256]
__global__ void k_build_emb(const int* __restrict__ tseq, const float* __restrict__ emb,
                            ushort* __restrict__ embbf) {
    int rid = blockIdx.x * 8 + (threadIdx.x >> 5);
    int c0 = (threadIdx.x & 31) * 8;
    int tok = tseq[rid];
    const float* src = emb + (size_t)tok * EMBED + c0;
    float4 v0 = *(const float4*)src;
    float4 v1 = *(const float4*)(src + 4);
    short8v o;
    o[0] = (short)f2bf(v0.x); o[1] = (short)f2bf(v0.y);
    o[2] = (short)f2bf(v0.z); o[3] = (short)f2bf(v0.w);
    o[4] = (short)f2bf(v1.x); o[5] = (short)f2bf(v1.y);
    o[6] = (short)f2bf(v1.z); o[7] = (short)f2bf(v1.w);
    *(short8v*)(embbf + (size_t)rid * EMBED + c0) = o;
}

__global__ void k_prep_small(const float* __restrict__ b_ih, const float* __restrict__ b_hh,
                             float* __restrict__ bias_pre,
                             const float* __restrict__ h0, ushort* __restrict__ hbufA,
                             const float* __restrict__ ctx, ushort* __restrict__ ctx_bf,
                             unsigned* __restrict__ ctrl) {
    int i = blockIdx.x * blockDim.x + threadIdx.x;
    if (i < 1024) ctrl[i] = 0;   // flags + queue zeroed every launch (replay-safe)
    if (i < G4) bias_pre[i] = b_ih[i] + b_hh[i];
    if (i < BB * HIDDEN) {
        hbufA[i] = f2bf(h0[i]);
        ctx_bf[i] = f2bf(ctx[i]);
    }
}

// Small-M GEMM: Cout[64][N] = Abf[64][512](bf16) @ Wf[N][.]^T(f32 strided) + bias[N].
__global__ __launch_bounds__(256) void k_gemm_smallM(
    const ushort* __restrict__ Abf, const float* __restrict__ Wf, int wstride,
    const float* __restrict__ bias, float* __restrict__ Cout, int N) {
    int t = threadIdx.x;
    int wv = t >> 6, lane = t & 63, lr = lane & 15, kg = lane >> 4;
    int bcol = blockIdx.x * 128;

    float4v acc[4][2];
#pragma unroll
    for (int m = 0; m < 4; m++)
#pragma unroll
        for (int n = 0; n < 2; n++) acc[m][n] = (float4v){0.f, 0.f, 0.f, 0.f};

#pragma unroll 4
    for (int ks = 0; ks < 16; ks++) {
        short8v a[4];
#pragma unroll
        for (int m = 0; m < 4; m++)
            a[m] = *(const short8v*)(Abf + (size_t)(m * 16 + lr) * 512 + ks * 32 + kg * 8);
        short8v w[2];
#pragma unroll
        for (int n = 0; n < 2; n++) {
            const float* src = Wf + (size_t)(bcol + wv * 32 + n * 16 + lr) * wstride + ks * 32 + kg * 8;
            float4 v0 = *(const float4*)src;
            float4 v1 = *(const float4*)(src + 4);
            short8v w8;
            w8[0] = (short)f2bf(v0.x); w8[1] = (short)f2bf(v0.y);
            w8[2] = (short)f2bf(v0.z); w8[3] = (short)f2bf(v0.w);
            w8[4] = (short)f2bf(v1.x); w8[5] = (short)f2bf(v1.y);
            w8[6] = (short)f2bf(v1.z); w8[7] = (short)f2bf(v1.w);
            w[n] = w8;
        }
#pragma unroll
        for (int m = 0; m < 4; m++)
#pragma unroll
            for (int n = 0; n < 2; n++)
                acc[m][n] = __builtin_amdgcn_mfma_f32_16x16x32_bf16(a[m], w[n], acc[m][n], 0, 0, 0);
    }

#pragma unroll
    for (int n = 0; n < 2; n++) {
        int col = bcol + wv * 32 + n * 16 + lr;
        float bv = bias[col];
#pragma unroll
        for (int m = 0; m < 4; m++) {
            int row = m * 16 + kg * 4;
#pragma unroll
            for (int j = 0; j < 4; j++)
                Cout[(size_t)(row + j) * N + col] = acc[m][n][j] + bv;
        }
    }
}

// Standalone 256x256 GEMM (pre only): C = A@W^T + rowbias[row>>6], b-major rows.
__global__ __launch_bounds__(512) void k_gemm_bf16(
    const ushort* __restrict__ A, const ushort* __restrict__ W,
    const float* __restrict__ rowbias, float* __restrict__ C,
    int M, int N, int K) {
    __shared__ ushort As[256 * 32];
    __shared__ ushort Ws[256 * 32];
    int t = threadIdx.x;

    int gx = N >> 8, gy = M >> 8;
    int nwg = gx * gy;
    int q = nwg >> 3, r = nwg & 7;
    int xcd = blockIdx.x & 7, idx = blockIdx.x >> 3;
    int wg = (xcd < r) ? xcd * (q + 1) + idx : r * (q + 1) + (xcd - r) * q + idx;
    const int SG = 4;
    int grp = wg / (gx * SG);
    int rem = wg % (gx * SG);
    int bx = rem / SG;
    int by = grp * SG + rem % SG;
    int brow = by * 256, bcol = bx * 256;

    int wave = t >> 6, lane = t & 63;
    int wr = wave >> 2, wc = wave & 3;
    int lr = lane & 15, kg = lane >> 4;

    float4v acc[8][4];
#pragma unroll
    for (int m = 0; m < 8; m++)
#pragma unroll
        for (int n = 0; n < 4; n++) acc[m][n] = (float4v){0.f, 0.f, 0.f, 0.f};

    int srow = t >> 2;
    int scol = (((t & 3) ^ (srow & 3))) * 8;
    const ushort* AgA = A + (size_t)(brow + srow) * K + scol;
    const ushort* AgB = A + (size_t)(brow + 128 + srow) * K + scol;
    const ushort* WgA = W + (size_t)(bcol + srow) * K + scol;
    const ushort* WgB = W + (size_t)(bcol + 128 + srow) * K + scol;
    ushort* ldsA0 = &As[(wave * 16) * 32];
    ushort* ldsA1 = &As[(128 + wave * 16) * 32];
    ushort* ldsW0 = &Ws[(wave * 16) * 32];
    ushort* ldsW1 = &Ws[(128 + wave * 16) * 32];

    for (int bk = 0; bk < K; bk += 32) {
        glds16(AgA + bk, ldsA0);
        glds16(AgB + bk, ldsA1);
        glds16(WgA + bk, ldsW0);
        glds16(WgB + bk, ldsW1);
        __syncthreads();
        short8v a[8], w[4];
#pragma unroll
        for (int m = 0; m < 8; m++) {
            int row = wr * 128 + m * 16 + lr;
            a[m] = *(const short8v*)&As[row * 32 + (kg ^ (row & 3)) * 8];
        }
#pragma unroll
        for (int n = 0; n < 4; n++) {
            int row = wc * 64 + n * 16 + lr;
            w[n] = *(const short8v*)&Ws[row * 32 + (kg ^ (row & 3)) * 8];
        }
#pragma unroll
        for (int m = 0; m < 8; m++)
#pragma unroll
            for (int n = 0; n < 4; n++)
                acc[m][n] = __builtin_amdgcn_mfma_f32_16x16x32_bf16(a[m], w[n], acc[m][n], 0, 0, 0);
        __syncthreads();
    }

#pragma unroll
    for (int n = 0; n < 4; n++) {
        int col = bcol + wc * 64 + n * 16 + lr;
#pragma unroll
        for (int m = 0; m < 8; m++) {
            int row = brow + wr * 128 + m * 16 + kg * 4;
            float bv = rowbias[(size_t)(row >> 6) * N + col];
            float4v v = acc[m][n];
#pragma unroll
            for (int j = 0; j < 4; j++)
                C[(size_t)(row + j) * N + col] = v[j] + bv;
        }
    }
}

// MEGA kernel: blocks 0..15 = persistent LSTM; blocks 16..255 = logits-GEMM
// workers (r15 structure). LSTM change vs r15: h is published ONCE per step
// (s-major out_in row (s*64+b) IS next step's h read) — the hbuf double-buffer
// store is deleted; s=0 reads the prep-filled hbufA. Same flag protocol.
// Workers: (hm 128-row group, chunk) items, LDS-resident A (sc0sc1, reload on
// hm change), cached-W glds16 K-loop, nontemporal C, s_sleep 64 gate backoff.
__global__ __launch_bounds__(512) void k_mega(
    const float* __restrict__ pre, const float* __restrict__ w_hh,
    const float* __restrict__ c0,
    ushort* __restrict__ hbufA,
    ushort* __restrict__ out_in, unsigned* __restrict__ ctrl,
    const ushort* __restrict__ Wfc, const float* __restrict__ ctxdot,
    float* __restrict__ Cout) {
    __shared__ __align__(16) char smem[147456];
    __shared__ int s_tile;
    unsigned* flags = ctrl;
    unsigned* queue = ctrl + 512;
    int t = threadIdx.x;
    int bid = blockIdx.x;
    int wave = t >> 6, lane = t & 63, lr = lane & 15, kg = lane >> 4;

    if (bid < NBLK) {
        // ================= LSTM path =================
        ushort* h_lds = (ushort*)smem;
        float* G2 = (float*)(smem + 65536);
        char* hl = (char*)h_lds;
        int p = bid;
        int w = wave;
        int mh = w >> 2, cw2 = w & 3;

        short8v wfrag[2][16];
#pragma unroll
        for (int ci = 0; ci < 2; ci++) {
            const float* wrow = w_hh + (size_t)(cw2 * HIDDEN + p * 32 + ci * 16 + lr) * HIDDEN;
#pragma unroll
            for (int ks = 0; ks < 16; ks++) {
                const float* src = wrow + ks * 32 + kg * 8;
                short8v w8;
#pragma unroll
                for (int e = 0; e < 8; e++) w8[e] = (short)f2bf(src[e]);
                wfrag[ci][ks] = w8;
            }
        }

        int b = t >> 3, jj0 = (t & 7) * 4, jg0 = p * 32 + jj0;
        float4v c_reg = *(const float4v*)(c0 + (size_t)b * HIDDEN + jg0);
        float4v pv[4];
#pragma unroll
        for (int qg = 0; qg < 4; qg++)
            pv[qg] = *(const float4v*)(pre + (size_t)(b * SS) * G4 + qg * HIDDEN + jg0);

        for (int s = 0; s < SS; s++) {
            // wait: all 16 producers completed step s-1 (parallel flag poll)
            if (s > 0) {
                const unsigned* fp = flags + (lane & 15) * 16;
                unsigned fv;
                do {
                    fv = __hip_atomic_load(fp, __ATOMIC_RELAXED, __HIP_MEMORY_SCOPE_AGENT);
                } while (__all((int)(fv >= (unsigned)s)) == 0);
            }

            // stage h: s=0 from prep hbufA (b-major); s>0 from out_in s-major
            // rows (s-1)*64 + b  — the previous step's single publish.
            {
                const ushort* hb = (s == 0) ? hbufA
                                            : out_in + (size_t)(s - 1) * BB * HIDDEN;
                uint4v vb[8];
#pragma unroll
                for (int i = 0; i < 8; i++) {
                    int rr = w * 8 + i;
                    const void* src = hb + (size_t)rr * HIDDEN + lane * 8;
                    asm volatile("global_load_dwordx4 %0, %1, off sc0 sc1"
                                 : "=&v"(vb[i]) : "v"(src));
                }
                asm volatile("s_waitcnt vmcnt(0)" ::: "memory");
#pragma unroll
                for (int i = 0; i < 8; i++) {
                    int rr = w * 8 + i;
                    int off = (rr * 1024 + lane * 16) ^ ((rr & 7) << 4);
                    *(uint4v*)(hl + off) = vb[i];
                }
            }
            __syncthreads();

            float4v acc[2][2];
#pragma unroll
            for (int mi = 0; mi < 2; mi++)
#pragma unroll
                for (int ci = 0; ci < 2; ci++) acc[mi][ci] = (float4v){0.f, 0.f, 0.f, 0.f};
#pragma unroll
            for (int ks = 0; ks < 16; ks++) {
                short8v a[2];
#pragma unroll
                for (int mi = 0; mi < 2; mi++) {
                    int row = mh * 32 + mi * 16 + lr;
                    int off = (row * 1024 + ks * 64 + kg * 16) ^ ((row & 7) << 4);
                    a[mi] = *(const short8v*)(hl + off);
                }
#pragma unroll
                for (int mi = 0; mi < 2; mi++)
#pragma unroll
                    for (int ci = 0; ci < 2; ci++)
                        acc[mi][ci] = __builtin_amdgcn_mfma_f32_16x16x32_bf16(a[mi], wfrag[ci][ks], acc[mi][ci], 0, 0, 0);
            }
#pragma unroll
            for (int mi = 0; mi < 2; mi++)
#pragma unroll
                for (int ci = 0; ci < 2; ci++)
#pragma unroll
                    for (int rr = 0; rr < 4; rr++)
                        G2[(mh * 32 + mi * 16 + kg * 4 + rr) * 132 + cw2 * 32 + ci * 16 + lr] = acc[mi][ci][rr];
            __syncthreads();

            {
                float4v gq[4];
#pragma unroll
                for (int qg = 0; qg < 4; qg++) gq[qg] = *(const float4v*)&G2[b * 132 + qg * 32 + jj0];
                unsigned long long hv8 = 0;
#pragma unroll
                for (int e = 0; e < 4; e++) {
                    float xi = gq[0][e] + pv[0][e];
                    float xf = gq[1][e] + pv[1][e];
                    float xg = gq[2][e] + pv[2][e];
                    float xo = gq[3][e] + pv[3][e];
                    float ig = 1.f / (1.f + __expf(-xi));
                    float fg = 1.f / (1.f + __expf(-xf));
                    float gg = fast_tanh(xg);
                    float og = 1.f / (1.f + __expf(-xo));
                    float cn = fg * c_reg[e] + ig * gg;
                    float hv = og * fast_tanh(cn);
                    c_reg[e] = cn;
                    hv8 |= (unsigned long long)f2bf(hv) << (16 * e);
                }
                // single publish: s-major out_in row (s*64+b) serves BOTH the
                // workers' A reads and the next LSTM step's h read
                __hip_atomic_store((unsigned long long*)(out_in + (size_t)(s * BB + b) * HIDDEN + jg0), hv8,
                                   __ATOMIC_RELAXED, __HIP_MEMORY_SCOPE_AGENT);
                if (s + 1 < SS) {
#pragma unroll
                    for (int qg = 0; qg < 4; qg++)
                        pv[qg] = *(const float4v*)(pre + (size_t)(b * SS + s + 1) * G4 + qg * HIDDEN + jg0);
                }
            }

            __syncthreads();   // drains all sc0sc1 stores (vmcnt) block-wide
            if (t == 0)
                __hip_atomic_store(flags + p * 16, (unsigned)(s + 1),
                                   __ATOMIC_RELEASE, __HIP_MEMORY_SCOPE_AGENT);
        }
    } else {
        // ================= GEMM worker path (r15) =================
        ushort* As = (ushort*)smem;               // 128KB resident A (swizzled)
        ushort* Ws = (ushort*)(smem + 131072);    // 16KB W staging
        char* al = (char*)As;
        int srow = t >> 2;                        // 0..127 (W staging row)
        int scolW = ((t & 3) ^ (srow & 3)) * 8;
        ushort* ldsW0 = Ws + (wave * 16) * 32;
        ushort* ldsW1 = Ws + (128 + wave * 16) * 32;
        int wr = wave >> 2, wc = wave & 3;
        int last_hm = -1, last_gated = -1;

        for (;;) {
            __syncthreads();
            if (t == 0)
                s_tile = (int)__hip_atomic_fetch_add(queue, 1u, __ATOMIC_RELAXED, __HIP_MEMORY_SCOPE_AGENT);
            __syncthreads();
            int item = s_tile;
            if (item >= NITEM) break;
            int hm, nt0, cnt;
            if (item < 750) { hm = item / 25; nt0 = (item % 25) * 5; cnt = 5; }
            else { int j = item - 750; hm = 30 + j / 125; nt0 = j % 125; cnt = 1; }

            int need = 2 * hm + 2;
            if (need > last_gated) {
                if (wave == 0) {
                    const unsigned* fp = flags + (lane & 15) * 16;
                    for (;;) {
                        unsigned fv = __hip_atomic_load(fp, __ATOMIC_RELAXED, __HIP_MEMORY_SCOPE_AGENT);
                        if (__all((int)(fv >= (unsigned)need))) break;
                        asm volatile("s_sleep 64");
                    }
                }
                __syncthreads();
                last_gated = need;
            }

            if (hm != last_hm) {
                // load A rows [hm*128, +128) into resident LDS (sc0sc1, swizzled)
                const ushort* Ab = out_in + (size_t)hm * 128 * HIDDEN;
#pragma unroll
                for (int half = 0; half < 2; half++) {
                    uint4v vb[8];
#pragma unroll
                    for (int i = 0; i < 8; i++) {
                        int rr = wave * 16 + half * 8 + i;
                        const void* src = Ab + (size_t)rr * HIDDEN + lane * 8;
                        asm volatile("global_load_dwordx4 %0, %1, off sc0 sc1"
                                     : "=&v"(vb[i]) : "v"(src));
                    }
                    asm volatile("s_waitcnt vmcnt(0)" ::: "memory");
#pragma unroll
                    for (int i = 0; i < 8; i++) {
                        int rr = wave * 16 + half * 8 + i;
                        int off = (rr * 1024 + lane * 16) ^ ((rr & 7) << 4);
                        *(uint4v*)(al + off) = vb[i];
                    }
                }
                __syncthreads();
                last_hm = hm;
            }

            for (int q5 = 0; q5 < cnt; q5++) {
                int nt = nt0 + q5;
                int bcol = nt * 256;

                float4v acc[4][4];
#pragma unroll
                for (int m = 0; m < 4; m++)
#pragma unroll
                    for (int n = 0; n < 4; n++) acc[m][n] = (float4v){0.f, 0.f, 0.f, 0.f};

                const ushort* WgA = Wfc + (size_t)(bcol + srow) * HIDDEN + scolW;
                const ushort* WgB = WgA + (size_t)128 * HIDDEN;

                for (int ks = 0; ks < 16; ks++) {
                    glds16(WgA + ks * 32, ldsW0);
                    glds16(WgB + ks * 32, ldsW1);
                    __syncthreads();
                    short8v a[4], w[4];
#pragma unroll
                    for (int m = 0; m < 4; m++) {
                        int row = wr * 64 + m * 16 + lr;
                        int off = (row * 1024 + ks * 64 + kg * 16) ^ ((row & 7) << 4);
                        a[m] = *(const short8v*)(al + off);
                    }
#pragma unroll
                    for (int n = 0; n < 4; n++) {
                        int wrow = wc * 64 + n * 16 + lr;
                        w[n] = *(const short8v*)&Ws[wrow * 32 + (kg ^ (wrow & 3)) * 8];
                    }
#pragma unroll
                    for (int m = 0; m < 4; m++)
#pragma unroll
                        for (int n = 0; n < 4; n++)
                            acc[m][n] = __builtin_amdgcn_mfma_f32_16x16x32_bf16(a[m], w[n], acc[m][n], 0, 0, 0);
                    __syncthreads();
                }

                // epilogue: local row rl -> (s = hm*2 + rl>>6, b = rl&63)
#pragma unroll
                for (int n = 0; n < 4; n++) {
                    int col = bcol + wc * 64 + n * 16 + lr;
#pragma unroll
                    for (int m = 0; m < 4; m++) {
                        int rbase = wr * 64 + m * 16 + kg * 4;
#pragma unroll
                        for (int j = 0; j < 4; j++) {
                            int rl = rbase + j;
                            int bb = rl & 63;
                            int ss = hm * 2 + (rl >> 6);
                            float val = acc[m][n][j] + ctxdot[(size_t)bb * VOCAB + col];
                            __builtin_nontemporal_store(val, &Cout[(size_t)(bb * 64 + ss) * VOCAB + col]);
                        }
                    }
                }
            }
        }
    }
}

extern "C" void kernel_launch(void* const* d_in, const int* in_sizes, int n_in,
                              void* d_out, int out_size, void* d_ws, size_t ws_size,
                              hipStream_t stream) {
    const int*   tseq = (const int*)d_in[0];
    const float* ctx  = (const float*)d_in[1];
    const float* h0   = (const float*)d_in[2];
    const float* c0   = (const float*)d_in[3];
    const float* emb  = (const float*)d_in[4];
    const float* w_ih = (const float*)d_in[5];
    const float* w_hh = (const float*)d_in[6];
    const float* b_ih = (const float*)d_in[7];
    const float* b_hh = (const float*)d_in[8];
    const float* w_fc = (const float*)d_in[9];
    const float* b_fc = (const float*)d_in[10];
    float* out = (float*)d_out;

    char* wsb = (char*)d_ws;
    size_t off = 0;
    auto alloc = [&](size_t bytes) -> void* {
        void* ptr = wsb + off;
        off = (off + bytes + 255) & ~(size_t)255;
        return ptr;
    };
    ushort* emb_bf    = (ushort*)alloc((size_t)M_ROWS * EMBED * 2);
    ushort* w_ih_ebf  = (ushort*)alloc((size_t)G4 * EMBED * 2);
    ushort* w_fc_hbf  = (ushort*)alloc((size_t)VOCAB * HIDDEN * 2);
    ushort* out_in    = (ushort*)alloc((size_t)M_ROWS * HIDDEN * 2);
    float*  pre       = (float*)alloc((size_t)M_ROWS * G4 * 4);
    float*  prectx    = (float*)alloc((size_t)BB * G4 * 4);
    float*  ctxdot    = (float*)alloc((size_t)BB * VOCAB * 4);
    ushort* ctx_bf    = (ushort*)alloc((size_t)BB * HIDDEN * 2);
    ushort* hbufA     = (ushort*)alloc((size_t)BB * HIDDEN * 2);
    float*  bias_pre  = (float*)alloc((size_t)G4 * 4);
    unsigned* ctrl    = (unsigned*)alloc(4096);

    k_conv_strided<<<256, 256, 0, stream>>>(w_ih, w_ih_ebf, 8, 768, G4 * EMBED / 8);
    k_conv_strided<<<2048, 256, 0, stream>>>(w_fc, w_fc_hbf, 9, 1024, VOCAB * HIDDEN / 8);
    k_build_emb<<<M_ROWS / 8, 256, 0, stream>>>(tseq, emb, emb_bf);
    k_prep_small<<<128, 256, 0, stream>>>(b_ih, b_hh, bias_pre, h0, hbufA, ctx, ctx_bf, ctrl);

    // ctx row-bias GEMMs (64 unique rows)
    k_gemm_smallM<<<G4 / 128, 256, 0, stream>>>(ctx_bf, w_ih + 256, 768, bias_pre, prectx, G4);
    k_gemm_smallM<<<VOCAB / 128, 256, 0, stream>>>(ctx_bf, w_fc + 512, 1024, b_fc, ctxdot, VOCAB);

    // pre = emb_bf @ w_ih_emb^T + prectx[b]   (K=256)
    k_gemm_bf16<<<dim3((G4 / 256) * (M_ROWS / 256)), 512, 0, stream>>>(
        emb_bf, w_ih_ebf, prectx, pre, M_ROWS, G4, EMBED);

    // fused LSTM + gated logits GEMM on all 256 CUs
    void* args[] = {(void*)&pre, (void*)&w_hh, (void*)&c0,
                    (void*)&hbufA, (void*)&out_in, (void*)&ctrl,
                    (void*)&w_fc_hbf, (void*)&ctxdot, (void*)&out};
    hipLaunchCooperativeKernel((void*)k_mega, dim3(NTOT), dim3(512), args, 0, stream);
}